// Round 2
// baseline (812.215 us; speedup 1.0000x reference)
//
#include <hip/hip_runtime.h>
#include <stdint.h>

// Sizes (fixed by the problem)
#define N_PATCH 8192
#define DIM     1024
#define HID     512
#define NHEAD   16

using short8 = __attribute__((ext_vector_type(8))) short;
using f32x4  = __attribute__((ext_vector_type(4))) float;

__device__ __forceinline__ unsigned short f2bf(float f) {
  unsigned u = __float_as_uint(f);
  u = u + 0x7fffu + ((u >> 16) & 1u);   // round-to-nearest-even
  return (unsigned short)(u >> 16);
}

// global -> LDS direct copy, 16B per lane (CK addrspace-cast pattern)
__device__ __forceinline__ void gload_lds16(const void* g, void* l) {
  __builtin_amdgcn_global_load_lds(
      reinterpret_cast<const __attribute__((address_space(1))) void*>(
          reinterpret_cast<uintptr_t>(g)),
      reinterpret_cast<__attribute__((address_space(3))) void*>(
          reinterpret_cast<uintptr_t>(l)),
      16, 0, 0);
}

// ---------------- x fp32 -> bf16 ----------------
__global__ void convert_x_kernel(const float* __restrict__ x,
                                 unsigned short* __restrict__ xb) {
  const int total4 = (N_PATCH * DIM) / 4;
  for (int i = blockIdx.x * blockDim.x + threadIdx.x; i < total4;
       i += gridDim.x * blockDim.x) {
    float4 v = ((const float4*)x)[i];
    ushort4 o;
    o.x = f2bf(v.x); o.y = f2bf(v.y); o.z = f2bf(v.z); o.w = f2bf(v.w);
    ((ushort4*)xb)[i] = o;
  }
}

// ---------------- pack Vw/Uw -> Wpt[k][c][d] bf16 (transposed, V/U interleaved per 16 cols) ----
// c = (h>>4)*32 + u*16 + (h&15),  u=0:V  u=1:U
__global__ void pack_w_kernel(const float* __restrict__ Vw,
                              const float* __restrict__ Uw,
                              unsigned short* __restrict__ Wpt) {
  __shared__ unsigned short T[128][68];
  const int hc = blockIdx.x;   // 0..7   (h chunk of 64)
  const int dc = blockIdx.y;   // 0..15  (d chunk of 64)
  const int k  = blockIdx.z;   // head
  const int t  = threadIdx.x;  // 256
  const int d0 = dc * 64, h0 = hc * 64;
  const size_t base = (size_t)k * DIM * HID;
  for (int u = 0; u < 2; ++u) {
    const float* W = u ? Uw : Vw;
    #pragma unroll
    for (int i = 0; i < 16; ++i) {
      int idx = i * 256 + t;
      int dd = idx >> 6, hh = idx & 63;
      float v = W[base + (size_t)(d0 + dd) * HID + h0 + hh];
      int cl = ((hh >> 4) << 5) + (u << 4) + (hh & 15);
      T[cl][dd] = f2bf(v);
    }
  }
  __syncthreads();
  const size_t obase = ((size_t)k * 1024 + hc * 128) * DIM + d0;
  #pragma unroll
  for (int i = 0; i < 8; ++i) {
    int idx = i * 1024 + t * 4;
    int cl = idx >> 6, dd = idx & 63;
    ushort4 o;
    o.x = T[cl][dd]; o.y = T[cl][dd + 1]; o.z = T[cl][dd + 2]; o.w = T[cl][dd + 3];
    *(ushort4*)&Wpt[obase + (size_t)cl * DIM + dd] = o;
  }
}

// ---------------- main GEMM + gated epilogue -> score partials ----------------
// 1D grid 8192: ct = bid & 7 (XCD-pinned column slice -> B panel fits 4MB L2),
//               idx = bid >> 3: mt = idx & 63, kh = idx >> 6.
// 128x128 tile, BK=64, 4 waves (2x2), SINGLE 32KB LDS buffer, 2 barriers/K-step (m97 structure).
__global__ __launch_bounds__(256, 4) void gemm_scores_kernel(
    const unsigned short* __restrict__ xb,
    const unsigned short* __restrict__ Wpt,
    const float* __restrict__ Vb, const float* __restrict__ Ub,
    const float* __restrict__ ww, float* __restrict__ part) {
  __shared__ unsigned short As[128 * 64];
  __shared__ unsigned short Bs[128 * 64];
  const int bid = blockIdx.x;
  const int ct = bid & 7;
  const int idx = bid >> 3;
  const int mt = idx & 63;
  const int kh = idx >> 6;
  const int tid = threadIdx.x;
  const int wv = tid >> 6, lane = tid & 63;
  const int wr = wv >> 1, wc = wv & 1;

  const unsigned short* Abase = xb + (size_t)mt * 128 * DIM;
  const unsigned short* Bbase = Wpt + ((size_t)kh * 1024 + ct * 128) * DIM;

  const f32x4 vzero = {0.f, 0.f, 0.f, 0.f};
  f32x4 acc[4][4];
  #pragma unroll
  for (int i = 0; i < 4; ++i)
    #pragma unroll
    for (int j = 0; j < 4; ++j) acc[i][j] = vzero;

  for (int kt = 0; kt < 16; ++kt) {
    // stage K-tile kt into the single buffer
    const int dbase = kt * 64;
    #pragma unroll
    for (int i = 0; i < 4; ++i) {
      const int flat = i * 4096 + tid * 16;  // byte offset in 16KB tile
      const int r = flat >> 7;               // 128B per row (64 bf16)
      const int cb = flat & 127;
      const int ldst = (i * 4096 + wv * 1024) >> 1;  // wave-uniform LDS base (ushorts)
      gload_lds16(Abase + (size_t)r * DIM + dbase + (cb >> 1), &As[ldst]);
      gload_lds16(Bbase + (size_t)r * DIM + dbase + (cb >> 1), &Bs[ldst]);
    }
    __syncthreads();   // compiler drains vmcnt(0) here -> staged data visible

    #pragma unroll
    for (int ks = 0; ks < 2; ++ks) {
      const int kb = ks * 32 + (lane >> 4) * 8;
      short8 a[4], b[4];
      #pragma unroll
      for (int i = 0; i < 4; ++i) {
        a[i] = *(const short8*)&As[(wr * 64 + i * 16 + (lane & 15)) * 64 + kb];
        b[i] = *(const short8*)&Bs[(wc * 64 + i * 16 + (lane & 15)) * 64 + kb];
      }
      #pragma unroll
      for (int i = 0; i < 4; ++i)
        #pragma unroll
        for (int j = 0; j < 4; ++j)
          acc[i][j] = __builtin_amdgcn_mfma_f32_16x16x32_bf16(a[i], b[j], acc[i][j], 0, 0, 0);
    }
    __syncthreads();   // protect LDS before next stage overwrites
  }

  // epilogue: tanh(AV+Vb)*sigmoid(AU+Ub)*ww, reduce over the 128 cols this block owns
  float partial[4][4];
  #pragma unroll
  for (int i = 0; i < 4; ++i)
    #pragma unroll
    for (int r = 0; r < 4; ++r) partial[i][r] = 0.f;

  #pragma unroll
  for (int p = 0; p < 2; ++p) {
    const int h = (ct * 4 + wc * 2 + p) * 16 + (lane & 15);
    const float vb = Vb[kh * HID + h];
    const float ub = Ub[kh * HID + h];
    const float wwv = ww[kh * HID + h];
    #pragma unroll
    for (int mi = 0; mi < 4; ++mi)
      #pragma unroll
      for (int r = 0; r < 4; ++r) {
        const float av = tanhf(acc[mi][2 * p][r] + vb);
        const float xu = acc[mi][2 * p + 1][r] + ub;
        const float au = 1.f / (1.f + __expf(-xu));
        partial[mi][r] += av * au * wwv;
      }
  }
  #pragma unroll
  for (int s = 1; s < 16; s <<= 1)
    #pragma unroll
    for (int mi = 0; mi < 4; ++mi)
      #pragma unroll
      for (int r = 0; r < 4; ++r)
        partial[mi][r] += __shfl_xor(partial[mi][r], s, 64);

  if ((lane & 15) == 0) {
    const int j = ct * 2 + wc;  // 0..15 partial slot
    float* dst = part + ((size_t)j * NHEAD + kh) * N_PATCH;
    const int rbase = mt * 128 + wr * 64 + (lane >> 4) * 4;
    #pragma unroll
    for (int mi = 0; mi < 4; ++mi)
      #pragma unroll
      for (int r = 0; r < 4; ++r)
        dst[rbase + mi * 16 + r] = partial[mi][r];
  }
}

// ---------------- per-head: sum partials -> softmax -> normalized A[k][n] ----------------
__global__ void head_softmax_kernel(const float* __restrict__ part,
                                    float* __restrict__ A) {
  const int k = blockIdx.x;
  const int t = threadIdx.x;
  __shared__ float shm[4], shs[4];
  float v[32];
  float mx = -1e30f;
  #pragma unroll
  for (int i = 0; i < 32; ++i) {
    const int n = i * 256 + t;
    float s = 0.f;
    #pragma unroll
    for (int j = 0; j < 16; ++j) s += part[((size_t)j * NHEAD + k) * N_PATCH + n];
    v[i] = s;
    mx = fmaxf(mx, s);
  }
  #pragma unroll
  for (int sft = 32; sft; sft >>= 1) mx = fmaxf(mx, __shfl_xor(mx, sft, 64));
  const int wv = t >> 6;
  if ((t & 63) == 0) shm[wv] = mx;
  __syncthreads();
  mx = fmaxf(fmaxf(shm[0], shm[1]), fmaxf(shm[2], shm[3]));
  float sum = 0.f;
  #pragma unroll
  for (int i = 0; i < 32; ++i) {
    v[i] = __expf(v[i] - mx);
    sum += v[i];
  }
  #pragma unroll
  for (int sft = 32; sft; sft >>= 1) sum += __shfl_xor(sum, sft, 64);
  if ((t & 63) == 0) shs[wv] = sum;
  __syncthreads();
  const float rz = 1.f / (shs[0] + shs[1] + shs[2] + shs[3]);
  #pragma unroll
  for (int i = 0; i < 32; ++i)
    A[(size_t)k * N_PATCH + i * 256 + t] = v[i] * rz;
}

// ---------------- wp1[nc][d]=sum_n w[n]x[n,d], wp2[nc][d]=sum_n x[n,d] ----------------
// w[n] = sum_k A[k][n], recomputed per block into LDS.
__global__ void wsum_part_kernel(const float* __restrict__ x,
                                 const float* __restrict__ A,
                                 float* __restrict__ wp1,
                                 float* __restrict__ wp2) {
  __shared__ float wrow[256];
  const int d = blockIdx.x * 256 + threadIdx.x;  // grid.x = 4
  const int nc = blockIdx.y;                     // 32 chunks of 256 rows
  {
    const int n = nc * 256 + threadIdx.x;
    float s = 0.f;
    #pragma unroll
    for (int k = 0; k < NHEAD; ++k) s += A[(size_t)k * N_PATCH + n];
    wrow[threadIdx.x] = s;
  }
  __syncthreads();
  float a1 = 0.f, a2 = 0.f;
  for (int i = 0; i < 256; ++i) {
    float xv = x[(size_t)(nc * 256 + i) * DIM + d];
    a1 += wrow[i] * xv;
    a2 += xv;
  }
  wp1[nc * DIM + d] = a1;
  wp2[nc * DIM + d] = a2;
}

__global__ void reduce_vec_kernel(const float* __restrict__ wp1,
                                  const float* __restrict__ wp2,
                                  float* __restrict__ y1,
                                  float* __restrict__ mvec) {
  int d = blockIdx.x * 256 + threadIdx.x;
  float s1 = 0.f, s2 = 0.f;
  #pragma unroll
  for (int i = 0; i < 32; ++i) {
    s1 += wp1[i * DIM + d];
    s2 += wp2[i * DIM + d];
  }
  y1[d] = s1;
  mvec[d] = s2 * (1.f / (float)N_PATCH);
}

// ---------------- full-K GEMV: out[j] = act((bias[j] + sum_d in[d]W[d,j] + extra[j])*scale) ----
__global__ void gemv_kernel(const float* __restrict__ in,
                            const float* __restrict__ W,
                            const float* __restrict__ bias,
                            const float* __restrict__ extra, float scale,
                            int do_relu, float* __restrict__ out, int In, int Out) {
  int j = blockIdx.x * 256 + threadIdx.x;
  if (j >= Out) return;
  float acc = bias[j];
  #pragma unroll 4
  for (int d = 0; d < In; ++d) acc += in[d] * W[(size_t)d * Out + j];
  if (extra) acc += extra[j];
  acc *= scale;
  if (do_relu) acc = fmaxf(acc, 0.f);
  out[j] = acc;
}

// ---------------- final: logits = c3 @ cW4 + cb4 ; softmax -> out ----------------
__global__ void final_head_kernel(const float* __restrict__ c3,
                                  const float* __restrict__ W,
                                  const float* __restrict__ b,
                                  float* __restrict__ out) {
  __shared__ float logits[9];
  int t = threadIdx.x;
  if (t < 9) {
    float acc = b[t];
    for (int d = 0; d < 256; ++d) acc += c3[d] * W[d * 9 + t];
    logits[t] = acc;
  }
  __syncthreads();
  if (t == 0) {
    float mx = logits[0];
    for (int j = 1; j < 9; ++j) mx = fmaxf(mx, logits[j]);
    float e[9], s = 0.f;
    for (int j = 0; j < 9; ++j) { e[j] = expf(logits[j] - mx); s += e[j]; }
    for (int j = 0; j < 9; ++j) out[j] = e[j] / s;
  }
}

extern "C" void kernel_launch(void* const* d_in, const int* in_sizes, int n_in,
                              void* d_out, int out_size, void* d_ws, size_t ws_size,
                              hipStream_t stream) {
  (void)in_sizes; (void)n_in; (void)out_size; (void)ws_size;
  const float* x   = (const float*)d_in[0];
  const float* Vw  = (const float*)d_in[1];
  const float* Vb  = (const float*)d_in[2];
  const float* Uw  = (const float*)d_in[3];
  const float* Ub  = (const float*)d_in[4];
  const float* ww  = (const float*)d_in[5];
  // d_in[6] = wb: constant per head -> softmax invariant -> unused
  const float* pW1 = (const float*)d_in[7];
  const float* pb1 = (const float*)d_in[8];
  const float* pW2 = (const float*)d_in[9];
  const float* pb2 = (const float*)d_in[10];
  const float* cW1 = (const float*)d_in[11];
  const float* cb1 = (const float*)d_in[12];
  const float* cW2 = (const float*)d_in[13];
  const float* cb2 = (const float*)d_in[14];
  const float* cW3 = (const float*)d_in[15];
  const float* cb3 = (const float*)d_in[16];
  const float* cW4 = (const float*)d_in[17];
  const float* cb4 = (const float*)d_in[18];
  float* out = (float*)d_out;

  char* ws = (char*)d_ws;
  size_t o = 0;
  auto alloc = [&](size_t bytes) -> char* {
    char* p = ws + o;
    o += (bytes + 255) & ~(size_t)255;
    return p;
  };
  unsigned short* xb  = (unsigned short*)alloc((size_t)N_PATCH * DIM * 2);      // 16 MB
  unsigned short* Wpt = (unsigned short*)alloc((size_t)NHEAD * 1024 * DIM * 2); // 32 MB
  float* part   = (float*)alloc((size_t)16 * NHEAD * N_PATCH * 4);              // 8 MB
  float* Amat   = (float*)alloc((size_t)NHEAD * N_PATCH * 4);
  float* wp1    = (float*)alloc(32 * DIM * 4);
  float* wp2    = (float*)alloc(32 * DIM * 4);
  float* y1     = (float*)alloc(DIM * 4);
  float* mvec   = (float*)alloc(DIM * 4);
  float* h1     = (float*)alloc(HID * 4);
  float* aggr   = (float*)alloc(DIM * 4);
  float* c1     = (float*)alloc(1024 * 4);
  float* c2     = (float*)alloc(512 * 4);
  float* c3     = (float*)alloc(256 * 4);

  convert_x_kernel<<<2048, 256, 0, stream>>>(x, xb);
  pack_w_kernel<<<dim3(8, 16, 16), 256, 0, stream>>>(Vw, Uw, Wpt);
  gemm_scores_kernel<<<8192, 256, 0, stream>>>(xb, Wpt, Vb, Ub, ww, part);
  head_softmax_kernel<<<16, 256, 0, stream>>>(part, Amat);
  wsum_part_kernel<<<dim3(4, 32), 256, 0, stream>>>(x, Amat, wp1, wp2);
  reduce_vec_kernel<<<4, 256, 0, stream>>>(wp1, wp2, y1, mvec);
  gemv_kernel<<<2, 256, 0, stream>>>(mvec, pW1, pb1, nullptr, 1.f, 1, h1, DIM, HID);
  gemv_kernel<<<4, 256, 0, stream>>>(h1, pW2, pb2, y1, 1.f / 17.f, 0, aggr, HID, DIM);
  gemv_kernel<<<4, 256, 0, stream>>>(aggr, cW1, cb1, nullptr, 1.f, 1, c1, 1024, 1024);
  gemv_kernel<<<2, 256, 0, stream>>>(c1, cW2, cb2, nullptr, 1.f, 1, c2, 1024, 512);
  gemv_kernel<<<1, 256, 0, stream>>>(c2, cW3, cb3, nullptr, 1.f, 1, c3, 512, 256);
  final_head_kernel<<<1, 64, 0, stream>>>(c3, cW4, cb4, out);
}

// Round 3
// 600.491 us; speedup vs baseline: 1.3526x; 1.3526x over previous
//
#include <hip/hip_runtime.h>
#include <stdint.h>

// Sizes (fixed by the problem)
#define N_PATCH 8192
#define DIM     1024
#define HID     512
#define NHEAD   16

using short8 = __attribute__((ext_vector_type(8))) short;
using f32x4  = __attribute__((ext_vector_type(4))) float;

#define VMC(n) asm volatile("s_waitcnt vmcnt(" #n ")" ::: "memory")
#define BAR()  __builtin_amdgcn_s_barrier()

__device__ __forceinline__ unsigned short f2bf(float f) {
  unsigned u = __float_as_uint(f);
  u = u + 0x7fffu + ((u >> 16) & 1u);   // round-to-nearest-even
  return (unsigned short)(u >> 16);
}

// global -> LDS direct copy, 16B per lane (CK addrspace-cast pattern)
__device__ __forceinline__ void gload_lds16(const void* g, void* l) {
  __builtin_amdgcn_global_load_lds(
      reinterpret_cast<const __attribute__((address_space(1))) void*>(
          reinterpret_cast<uintptr_t>(g)),
      reinterpret_cast<__attribute__((address_space(3))) void*>(
          reinterpret_cast<uintptr_t>(l)),
      16, 0, 0);
}

// ---------------- x fp32 -> bf16 ----------------
__global__ void convert_x_kernel(const float* __restrict__ x,
                                 unsigned short* __restrict__ xb) {
  const int total4 = (N_PATCH * DIM) / 4;
  for (int i = blockIdx.x * blockDim.x + threadIdx.x; i < total4;
       i += gridDim.x * blockDim.x) {
    float4 v = ((const float4*)x)[i];
    ushort4 o;
    o.x = f2bf(v.x); o.y = f2bf(v.y); o.z = f2bf(v.z); o.w = f2bf(v.w);
    ((ushort4*)xb)[i] = o;
  }
}

// ---------------- pack Vw/Uw -> Wpt[k][c][d] bf16 (transposed, V/U interleaved per 16 cols) ----
// c = (h>>4)*32 + u*16 + (h&15),  u=0:V  u=1:U
__global__ void pack_w_kernel(const float* __restrict__ Vw,
                              const float* __restrict__ Uw,
                              unsigned short* __restrict__ Wpt) {
  __shared__ unsigned short T[128][68];
  const int hc = blockIdx.x;   // 0..7   (h chunk of 64)
  const int dc = blockIdx.y;   // 0..15  (d chunk of 64)
  const int k  = blockIdx.z;   // head
  const int t  = threadIdx.x;  // 256
  const int d0 = dc * 64, h0 = hc * 64;
  const size_t base = (size_t)k * DIM * HID;
  for (int u = 0; u < 2; ++u) {
    const float* W = u ? Uw : Vw;
    #pragma unroll
    for (int i = 0; i < 16; ++i) {
      int idx = i * 256 + t;
      int dd = idx >> 6, hh = idx & 63;
      float v = W[base + (size_t)(d0 + dd) * HID + h0 + hh];
      int cl = ((hh >> 4) << 5) + (u << 4) + (hh & 15);
      T[cl][dd] = f2bf(v);
    }
  }
  __syncthreads();
  const size_t obase = ((size_t)k * 1024 + hc * 128) * DIM + d0;
  #pragma unroll
  for (int i = 0; i < 8; ++i) {
    int idx = i * 1024 + t * 4;
    int cl = idx >> 6, dd = idx & 63;
    ushort4 o;
    o.x = T[cl][dd]; o.y = T[cl][dd + 1]; o.z = T[cl][dd + 2]; o.w = T[cl][dd + 3];
    *(ushort4*)&Wpt[obase + (size_t)cl * DIM + dd] = o;
  }
}

// ---------------- main GEMM + gated epilogue -> score partials ----------------
// 256x256 tile, BK=64, 8 waves (2M x 4N), 8-phase schedule, chunked staging,
// counted vmcnt (steady-state 8), XOR LDS swizzle, XCD-chunked block mapping.
// Grid: 2048 blocks of 512. Logical: ct = (bid&7)*8 + (bid>>8), mt = (bid>>3)&31.
__global__ __launch_bounds__(512, 2) void gemm_scores_kernel(
    const unsigned short* __restrict__ xb,
    const unsigned short* __restrict__ Wpt,
    const float* __restrict__ Vb, const float* __restrict__ Ub,
    const float* __restrict__ ww, float* __restrict__ part) {
  __shared__ unsigned short As[2][256 * 64];   // 64 KB
  __shared__ unsigned short Bs[2][256 * 64];   // 64 KB
  const int bid = blockIdx.x;
  const int ct = (bid & 7) * 8 + (bid >> 8);   // XCD-chunked: 8 col-panels per XCD
  const int mt = (bid >> 3) & 31;
  const int kh = ct >> 2, cb = ct & 3;
  const int tid = threadIdx.x;
  const int wv = tid >> 6, lane = tid & 63;
  const int wr = wv >> 2, wc = wv & 3;         // 2 x 4 wave grid
  const int l15 = lane & 15, l4 = lane >> 4;

  const unsigned short* Ab = xb + (size_t)mt * 256 * DIM;
  const unsigned short* Bb = Wpt + (size_t)ct * 256 * DIM;

  const f32x4 vzero = {0.f, 0.f, 0.f, 0.f};
  f32x4 acc[8][4];
  #pragma unroll
  for (int i = 0; i < 8; ++i)
    #pragma unroll
    for (int j = 0; j < 4; ++j) acc[i][j] = vzero;

  // ---- staging: chunk = 16KB, 2 x gload_lds16 per thread, linear LDS dest,
  //      inverse-swizzled global source (k ^= ((r>>2)&3)<<4) ----
  auto stageA = [&](int t, int mh) {   // A rows with (r>>6)&1 == mh
    const int buf = t & 1, db = t << 6;
    #pragma unroll
    for (int j = 0; j < 2; ++j) {
      const int r = j * 128 + mh * 64 + wv * 8 + (lane >> 3);
      const int ksrc = ((lane & 7) * 8) ^ (((r >> 2) & 3) << 4);
      char* lds = (char*)&As[buf][0] + j * 16384 + mh * 8192 + wv * 1024;
      gload_lds16(Ab + (size_t)r * DIM + db + ksrc, lds);
    }
  };
  auto stageB = [&](int t, int nh) {   // B rows with (r>>5)&1 == nh
    const int buf = t & 1, db = t << 6;
    #pragma unroll
    for (int j = 0; j < 2; ++j) {
      const int piece = j * 2 + wr;
      const int r = piece * 64 + nh * 32 + (wv & 3) * 8 + (lane >> 3);
      const int ksrc = ((lane & 7) * 8) ^ (((r >> 2) & 3) << 4);
      char* lds = (char*)&Bs[buf][0] + piece * 8192 + nh * 4096 + (wv & 3) * 1024;
      gload_lds16(Bb + (size_t)r * DIM + db + ksrc, lds);
    }
  };

  short8 a[8], b[4];
  auto LDA = [&](int buf, int mh) {   // 8 x ds_read_b128 (swizzled)
    #pragma unroll
    for (int f = 0; f < 4; ++f)
      #pragma unroll
      for (int ks = 0; ks < 2; ++ks) {
        const int r = wr * 128 + (mh * 4 + f) * 16 + l15;
        int byte = (r << 7) + ((ks * 32 + l4 * 8) << 1);
        byte ^= ((r >> 2) & 3) << 5;
        a[f * 2 + ks] = *(const short8*)((const char*)&As[buf][0] + byte);
      }
  };
  auto LDB = [&](int buf, int nh) {   // 4 x ds_read_b128 (swizzled)
    #pragma unroll
    for (int g = 0; g < 2; ++g)
      #pragma unroll
      for (int ks = 0; ks < 2; ++ks) {
        const int r = wc * 64 + (nh * 2 + g) * 16 + l15;
        int byte = (r << 7) + ((ks * 32 + l4 * 8) << 1);
        byte ^= ((r >> 2) & 3) << 5;
        b[g * 2 + ks] = *(const short8*)((const char*)&Bs[buf][0] + byte);
      }
  };
  auto MFMAQ = [&](int mh, int nh) {  // 16 MFMA: one C-quadrant x K=64
    __builtin_amdgcn_s_setprio(1);
    #pragma unroll
    for (int ks = 0; ks < 2; ++ks)
      #pragma unroll
      for (int f = 0; f < 4; ++f)
        #pragma unroll
        for (int g = 0; g < 2; ++g)
          acc[mh * 4 + f][nh * 2 + g] = __builtin_amdgcn_mfma_f32_16x16x32_bf16(
              a[f * 2 + ks], b[g * 2 + ks], acc[mh * 4 + f][nh * 2 + g], 0, 0, 0);
    __builtin_amdgcn_s_setprio(0);
  };

  // ---- prologue: queue = [A0(0),A1(0),B0(0),B1(0),A0(1),A1(1),B0(1)] (14 loads)
  stageA(0, 0); stageA(0, 1); stageB(0, 0); stageB(0, 1);
  stageA(1, 0); stageA(1, 1); stageB(1, 0);
  VMC(8);   // drain A0(0),A1(0),B0(0)
  BAR();

  // ---- main loop: K-tiles u=0..13 (stages always valid, u+2 <= 15) ----
  for (int u = 0; u < 14; ++u) {
    const int buf = u & 1;
    // ph0 (mh0,nh0): needs A0(u),B0(u); stages B1(u+1) into other buf
    LDA(buf, 0); LDB(buf, 0); stageB(u + 1, 1);
    BAR(); MFMAQ(0, 0); VMC(8); BAR();
    // ph1 (mh0,nh1): needs B1(u) [drained by VMC above]; stages A0(u+2)
    LDB(buf, 1); stageA(u + 2, 0);
    BAR(); MFMAQ(0, 1); BAR();
    // ph2 (mh1,nh0): needs A1(u) [already drained]
    LDA(buf, 1); LDB(buf, 0);
    BAR(); MFMAQ(1, 0); BAR();
    // ph3 (mh1,nh1): stages A1(u+2), B0(u+2)
    LDB(buf, 1); stageA(u + 2, 1); stageB(u + 2, 0);
    BAR(); MFMAQ(1, 1); VMC(8); BAR();
  }
  // ---- u = 14: only B1(15) left to stage; tail-drain vmcnt(2) ----
  {
    LDA(0, 0); LDB(0, 0); stageB(15, 1);
    BAR(); MFMAQ(0, 0); VMC(8); BAR();
    LDB(0, 1);
    BAR(); MFMAQ(0, 1); BAR();
    LDA(0, 1); LDB(0, 0);
    BAR(); MFMAQ(1, 0); BAR();
    LDB(0, 1);
    BAR(); MFMAQ(1, 1); VMC(2); BAR();
  }
  // ---- u = 15: no staging; vmcnt(0) after ph0 covers B1(15) ----
  {
    LDA(1, 0); LDB(1, 0);
    BAR(); MFMAQ(0, 0); VMC(0); BAR();
    LDB(1, 1);
    BAR(); MFMAQ(0, 1); BAR();
    LDA(1, 1); LDB(1, 0);
    BAR(); MFMAQ(1, 0); BAR();
    LDB(1, 1);
    BAR(); MFMAQ(1, 1); BAR();
  }

  // ---- gated epilogue: tanh(AV+Vb)*sigmoid(AU+Ub)*ww, reduce 16 lanes ----
  float partial[8][4];
  #pragma unroll
  for (int f = 0; f < 8; ++f)
    #pragma unroll
    for (int r = 0; r < 4; ++r) partial[f][r] = 0.f;

  #pragma unroll
  for (int p = 0; p < 2; ++p) {
    const int hl = (cb * 8 + wc * 2 + p) * 16 + l15;   // head-local h
    const float vb  = Vb[kh * HID + hl];
    const float ub  = Ub[kh * HID + hl];
    const float wwv = ww[kh * HID + hl];
    #pragma unroll
    for (int f = 0; f < 8; ++f)
      #pragma unroll
      for (int r = 0; r < 4; ++r) {
        const float av = tanhf(acc[f][2 * p][r] + vb);
        const float xu = acc[f][2 * p + 1][r] + ub;
        const float au = 1.f / (1.f + __expf(-xu));
        partial[f][r] += av * au * wwv;
      }
  }
  #pragma unroll
  for (int s = 1; s < 16; s <<= 1)
    #pragma unroll
    for (int f = 0; f < 8; ++f)
      #pragma unroll
      for (int r = 0; r < 4; ++r)
        partial[f][r] += __shfl_xor(partial[f][r], s, 64);

  if (l15 == 0) {
    const int j = cb * 4 + wc;   // 0..15 partial slot
    float* dst = part + ((size_t)j * NHEAD + kh) * N_PATCH;
    const int rbase = mt * 256 + wr * 128 + l4 * 4;
    #pragma unroll
    for (int f = 0; f < 8; ++f)
      #pragma unroll
      for (int r = 0; r < 4; ++r)
        dst[rbase + f * 16 + r] = partial[f][r];
  }
}

// ---------------- scores = sum of 16 partials ----------------
__global__ void reduce_scores_kernel(const float* __restrict__ part,
                                     float* __restrict__ scores) {
  int idx = blockIdx.x * 256 + threadIdx.x;  // 131072 = 16*8192
  int k = idx >> 13, n = idx & 8191;
  float s = 0.f;
  #pragma unroll
  for (int j = 0; j < 16; ++j) s += part[((size_t)j * NHEAD + k) * N_PATCH + n];
  scores[idx] = s;
}

// ---------------- per-head softmax stats (max, sumexp) ----------------
__global__ void softmax_stats_kernel(const float* __restrict__ scores,
                                     float* __restrict__ stats) {
  const int k = blockIdx.x;
  const float* s = scores + (size_t)k * N_PATCH;
  __shared__ float shm[4], shs[4];
  float v[32];
  float mx = -1e30f;
  #pragma unroll
  for (int i = 0; i < 32; ++i) {
    v[i] = s[i * 256 + threadIdx.x];
    mx = fmaxf(mx, v[i]);
  }
  #pragma unroll
  for (int sft = 32; sft; sft >>= 1) mx = fmaxf(mx, __shfl_xor(mx, sft, 64));
  const int wv = threadIdx.x >> 6;
  if ((threadIdx.x & 63) == 0) shm[wv] = mx;
  __syncthreads();
  mx = fmaxf(fmaxf(shm[0], shm[1]), fmaxf(shm[2], shm[3]));
  float sum = 0.f;
  #pragma unroll
  for (int i = 0; i < 32; ++i) sum += __expf(v[i] - mx);
  #pragma unroll
  for (int sft = 32; sft; sft >>= 1) sum += __shfl_xor(sum, sft, 64);
  if ((threadIdx.x & 63) == 0) shs[wv] = sum;
  __syncthreads();
  if (threadIdx.x == 0) {
    stats[2 * k] = mx;
    stats[2 * k + 1] = shs[0] + shs[1] + shs[2] + shs[3];
  }
}

// ---------------- w[n] = sum_k softmax_k(n) ----------------
__global__ void compute_w_kernel(const float* __restrict__ scores,
                                 const float* __restrict__ stats,
                                 float* __restrict__ w) {
  int n = blockIdx.x * 256 + threadIdx.x;
  float acc = 0.f;
  #pragma unroll
  for (int k = 0; k < NHEAD; ++k) {
    float rl = 1.f / stats[2 * k + 1];
    acc += __expf(scores[(size_t)k * N_PATCH + n] - stats[2 * k]) * rl;
  }
  w[n] = acc;
}

// ---------------- y1[d]=sum w[n]x[n,d], y2[d]=sum x[n,d]  (partials) ----------------
__global__ void weighted_part_kernel(const float* __restrict__ x,
                                     const float* __restrict__ w,
                                     float* __restrict__ wp1,
                                     float* __restrict__ wp2) {
  const int d = blockIdx.x * 256 + threadIdx.x;  // grid.x = 4
  const int nc = blockIdx.y;                     // 32 chunks of 256 rows
  float a1 = 0.f, a2 = 0.f;
  for (int i = 0; i < 256; ++i) {
    int n = nc * 256 + i;
    float xv = x[(size_t)n * DIM + d];
    a1 += w[n] * xv;
    a2 += xv;
  }
  wp1[nc * DIM + d] = a1;
  wp2[nc * DIM + d] = a2;
}

__global__ void reduce_vec_kernel(const float* __restrict__ wp1,
                                  const float* __restrict__ wp2,
                                  float* __restrict__ y1,
                                  float* __restrict__ mvec) {
  int d = blockIdx.x * 256 + threadIdx.x;
  float s1 = 0.f, s2 = 0.f;
  #pragma unroll
  for (int i = 0; i < 32; ++i) {
    s1 += wp1[i * DIM + d];
    s2 += wp2[i * DIM + d];
  }
  y1[d] = s1;
  mvec[d] = s2 * (1.f / (float)N_PATCH);
}

// ---------------- split-K GEMV partial: part[kc][j] = sum_{d in chunk} in[d]*W[d,j] ----------
__global__ void gemv_part_kernel(const float* __restrict__ in,
                                 const float* __restrict__ W,
                                 float* __restrict__ part, int In, int Out) {
  int j = blockIdx.x * blockDim.x + threadIdx.x;
  int kc = blockIdx.y;
  int chunk = In / gridDim.y;
  if (j >= Out) return;
  const float* Wp = W + (size_t)(kc * chunk) * Out + j;
  float acc = 0.f;
  for (int d = 0; d < chunk; ++d) acc += in[kc * chunk + d] * Wp[(size_t)d * Out];
  part[kc * Out + j] = acc;
}

__global__ void gemv_combine_kernel(const float* __restrict__ part, int nkc,
                                    const float* __restrict__ bias,
                                    const float* __restrict__ extra, float scale,
                                    int do_relu, float* __restrict__ out, int Out) {
  int j = blockIdx.x * blockDim.x + threadIdx.x;
  if (j >= Out) return;
  float v = bias[j];
  for (int kc = 0; kc < nkc; ++kc) v += part[kc * Out + j];
  if (extra) v += extra[j];
  v *= scale;
  if (do_relu) v = fmaxf(v, 0.f);
  out[j] = v;
}

// ---------------- final: logits = c3 @ cW4 + cb4 ; softmax -> out ----------------
__global__ void final_head_kernel(const float* __restrict__ c3,
                                  const float* __restrict__ W,
                                  const float* __restrict__ b,
                                  float* __restrict__ out) {
  __shared__ float logits[9];
  int t = threadIdx.x;
  if (t < 9) {
    float acc = b[t];
    for (int d = 0; d < 256; ++d) acc += c3[d] * W[d * 9 + t];
    logits[t] = acc;
  }
  __syncthreads();
  if (t == 0) {
    float mx = logits[0];
    for (int j = 1; j < 9; ++j) mx = fmaxf(mx, logits[j]);
    float e[9], s = 0.f;
    for (int j = 0; j < 9; ++j) { e[j] = expf(logits[j] - mx); s += e[j]; }
    for (int j = 0; j < 9; ++j) out[j] = e[j] / s;
  }
}

extern "C" void kernel_launch(void* const* d_in, const int* in_sizes, int n_in,
                              void* d_out, int out_size, void* d_ws, size_t ws_size,
                              hipStream_t stream) {
  (void)in_sizes; (void)n_in; (void)out_size; (void)ws_size;
  const float* x   = (const float*)d_in[0];
  const float* Vw  = (const float*)d_in[1];
  const float* Vb  = (const float*)d_in[2];
  const float* Uw  = (const float*)d_in[3];
  const float* Ub  = (const float*)d_in[4];
  const float* ww  = (const float*)d_in[5];
  // d_in[6] = wb: constant per head -> softmax invariant -> unused
  const float* pW1 = (const float*)d_in[7];
  const float* pb1 = (const float*)d_in[8];
  const float* pW2 = (const float*)d_in[9];
  const float* pb2 = (const float*)d_in[10];
  const float* cW1 = (const float*)d_in[11];
  const float* cb1 = (const float*)d_in[12];
  const float* cW2 = (const float*)d_in[13];
  const float* cb2 = (const float*)d_in[14];
  const float* cW3 = (const float*)d_in[15];
  const float* cb3 = (const float*)d_in[16];
  const float* cW4 = (const float*)d_in[17];
  const float* cb4 = (const float*)d_in[18];
  float* out = (float*)d_out;

  char* ws = (char*)d_ws;
  size_t o = 0;
  auto alloc = [&](size_t bytes) -> char* {
    char* p = ws + o;
    o += (bytes + 255) & ~(size_t)255;
    return p;
  };
  unsigned short* xb  = (unsigned short*)alloc((size_t)N_PATCH * DIM * 2);      // 16 MB
  unsigned short* Wpt = (unsigned short*)alloc((size_t)NHEAD * 1024 * DIM * 2); // 32 MB
  float* part   = (float*)alloc((size_t)16 * NHEAD * N_PATCH * 4);              // 8 MB
  float* scores = (float*)alloc((size_t)NHEAD * N_PATCH * 4);
  float* stats  = (float*)alloc(NHEAD * 2 * 4);
  float* wvec   = (float*)alloc(N_PATCH * 4);
  float* wp1    = (float*)alloc(32 * DIM * 4);
  float* wp2    = (float*)alloc(32 * DIM * 4);
  float* y1     = (float*)alloc(DIM * 4);
  float* mvec   = (float*)alloc(DIM * 4);
  float* h1part = (float*)alloc(8 * HID * 4);
  float* h1     = (float*)alloc(HID * 4);
  float* agpart = (float*)alloc(4 * DIM * 4);
  float* aggr   = (float*)alloc(DIM * 4);
  float* c1part = (float*)alloc(8 * 1024 * 4);
  float* c1     = (float*)alloc(1024 * 4);
  float* c2part = (float*)alloc(8 * 512 * 4);
  float* c2     = (float*)alloc(512 * 4);
  float* c3part = (float*)alloc(4 * 256 * 4);
  float* c3     = (float*)alloc(256 * 4);

  convert_x_kernel<<<2048, 256, 0, stream>>>(x, xb);
  pack_w_kernel<<<dim3(8, 16, 16), 256, 0, stream>>>(Vw, Uw, Wpt);
  gemm_scores_kernel<<<2048, 512, 0, stream>>>(xb, Wpt, Vb, Ub, ww, part);
  reduce_scores_kernel<<<512, 256, 0, stream>>>(part, scores);
  softmax_stats_kernel<<<16, 256, 0, stream>>>(scores, stats);
  compute_w_kernel<<<32, 256, 0, stream>>>(scores, stats, wvec);
  weighted_part_kernel<<<dim3(4, 32), 256, 0, stream>>>(x, wvec, wp1, wp2);
  reduce_vec_kernel<<<4, 256, 0, stream>>>(wp1, wp2, y1, mvec);
  gemv_part_kernel<<<dim3(2, 8), 256, 0, stream>>>(mvec, pW1, h1part, DIM, HID);
  gemv_combine_kernel<<<2, 256, 0, stream>>>(h1part, 8, pb1, nullptr, 1.f, 1, h1, HID);
  gemv_part_kernel<<<dim3(4, 4), 256, 0, stream>>>(h1, pW2, agpart, HID, DIM);
  gemv_combine_kernel<<<4, 256, 0, stream>>>(agpart, 4, pb2, y1, 1.f / 17.f, 0, aggr, DIM);
  gemv_part_kernel<<<dim3(4, 8), 256, 0, stream>>>(aggr, cW1, c1part, 1024, 1024);
  gemv_combine_kernel<<<4, 256, 0, stream>>>(c1part, 8, cb1, nullptr, 1.f, 1, c1, 1024);
  gemv_part_kernel<<<dim3(2, 8), 256, 0, stream>>>(c1, cW2, c2part, 1024, 512);
  gemv_combine_kernel<<<2, 256, 0, stream>>>(c2part, 8, cb2, nullptr, 1.f, 1, c2, 512);
  gemv_part_kernel<<<dim3(1, 4), 256, 0, stream>>>(c2, cW3, c3part, 512, 256);
  gemv_combine_kernel<<<1, 256, 0, stream>>>(c3part, 4, cb3, nullptr, 1.f, 1, c3, 256);
  final_head_kernel<<<1, 64, 0, stream>>>(c3, cW4, cb4, out);
}

// Round 4
// 556.167 us; speedup vs baseline: 1.4604x; 1.0797x over previous
//
#include <hip/hip_runtime.h>
#include <stdint.h>

// Sizes (fixed by the problem)
#define N_PATCH 8192
#define DIM     1024
#define HID     512
#define NHEAD   16

using short8 = __attribute__((ext_vector_type(8))) short;
using f32x4  = __attribute__((ext_vector_type(4))) float;

#define VMC(n) asm volatile("s_waitcnt vmcnt(" #n ")" ::: "memory")
#define BAR()  __builtin_amdgcn_s_barrier()

__device__ __forceinline__ unsigned short f2bf(float f) {
  unsigned u = __float_as_uint(f);
  u = u + 0x7fffu + ((u >> 16) & 1u);   // round-to-nearest-even
  return (unsigned short)(u >> 16);
}

// global -> LDS direct copy, 16B per lane (CK addrspace-cast pattern)
__device__ __forceinline__ void gload_lds16(const void* g, void* l) {
  __builtin_amdgcn_global_load_lds(
      reinterpret_cast<const __attribute__((address_space(1))) void*>(
          reinterpret_cast<uintptr_t>(g)),
      reinterpret_cast<__attribute__((address_space(3))) void*>(
          reinterpret_cast<uintptr_t>(l)),
      16, 0, 0);
}

// ---------------- x fp32 -> bf16 ----------------
__global__ void convert_x_kernel(const float* __restrict__ x,
                                 unsigned short* __restrict__ xb) {
  const int total4 = (N_PATCH * DIM) / 4;
  for (int i = blockIdx.x * blockDim.x + threadIdx.x; i < total4;
       i += gridDim.x * blockDim.x) {
    float4 v = ((const float4*)x)[i];
    ushort4 o;
    o.x = f2bf(v.x); o.y = f2bf(v.y); o.z = f2bf(v.z); o.w = f2bf(v.w);
    ((ushort4*)xb)[i] = o;
  }
}

// ---------------- pack Vw/Uw -> Wpt[k][c][d] bf16 (transposed, V/U interleaved per 16 cols) ----
// c = (h>>4)*32 + u*16 + (h&15),  u=0:V  u=1:U
__global__ void pack_w_kernel(const float* __restrict__ Vw,
                              const float* __restrict__ Uw,
                              unsigned short* __restrict__ Wpt) {
  __shared__ unsigned short T[128][68];
  const int hc = blockIdx.x;   // 0..7   (h chunk of 64)
  const int dc = blockIdx.y;   // 0..15  (d chunk of 64)
  const int k  = blockIdx.z;   // head
  const int t  = threadIdx.x;  // 256
  const int d0 = dc * 64, h0 = hc * 64;
  const size_t base = (size_t)k * DIM * HID;
  for (int u = 0; u < 2; ++u) {
    const float* W = u ? Uw : Vw;
    #pragma unroll
    for (int i = 0; i < 16; ++i) {
      int idx = i * 256 + t;
      int dd = idx >> 6, hh = idx & 63;
      float v = W[base + (size_t)(d0 + dd) * HID + h0 + hh];
      int cl = ((hh >> 4) << 5) + (u << 4) + (hh & 15);
      T[cl][dd] = f2bf(v);
    }
  }
  __syncthreads();
  const size_t obase = ((size_t)k * 1024 + hc * 128) * DIM + d0;
  #pragma unroll
  for (int i = 0; i < 8; ++i) {
    int idx = i * 1024 + t * 4;
    int cl = idx >> 6, dd = idx & 63;
    ushort4 o;
    o.x = T[cl][dd]; o.y = T[cl][dd + 1]; o.z = T[cl][dd + 2]; o.w = T[cl][dd + 3];
    *(ushort4*)&Wpt[obase + (size_t)cl * DIM + dd] = o;
  }
}

// ---------------- main GEMM + gated epilogue -> score partials ----------------
// 256x256 tile, BK=64, 8 waves (2M x 4N), 8-phase, 3-bit XOR swizzle (conflict-free
// ds_read_b128), B read once per K-tile (held in regs), one counted vmcnt(8)/K-tile.
__global__ __launch_bounds__(512, 2) void gemm_scores_kernel(
    const unsigned short* __restrict__ xb,
    const unsigned short* __restrict__ Wpt,
    const float* __restrict__ Vb, const float* __restrict__ Ub,
    const float* __restrict__ ww, float* __restrict__ part) {
  __shared__ unsigned short As[2][16384];   // 64 KB
  __shared__ unsigned short Bs[2][16384];   // 64 KB
  const int bid = blockIdx.x;
  const int ct = (bid & 7) * 8 + (bid >> 8);   // XCD-chunked: 8 col-panels per XCD
  const int mt = (bid >> 3) & 31;
  const int kh = ct >> 2, cb = ct & 3;
  const int tid = threadIdx.x;
  const int wv = tid >> 6, lane = tid & 63;
  const int wr = wv >> 2, wc = wv & 3;         // 2 x 4 wave grid
  const int l15 = lane & 15, l4 = lane >> 4;

  const unsigned short* Ab = xb + (size_t)mt * 256 * DIM;
  const unsigned short* Bb = Wpt + (size_t)ct * 256 * DIM;

  const f32x4 vzero = {0.f, 0.f, 0.f, 0.f};
  f32x4 acc[8][4];
  #pragma unroll
  for (int i = 0; i < 8; ++i)
    #pragma unroll
    for (int j = 0; j < 4; ++j) acc[i][j] = vzero;

  // ---- staging: chunk = 16KB, 2 x gload_lds16 per thread, linear LDS dest,
  //      inverse-swizzled global source (elem k ^= ((r>>1)&7)<<3) ----
  auto stageA = [&](int t, int mh) {
    const int buf = t & 1, db = t << 6;
    #pragma unroll
    for (int j = 0; j < 2; ++j) {
      const int r = j * 128 + mh * 64 + wv * 8 + (lane >> 3);
      const int ksrc = ((lane & 7) * 8) ^ (((r >> 1) & 7) << 3);
      char* lds = (char*)&As[buf][0] + j * 16384 + mh * 8192 + wv * 1024;
      gload_lds16(Ab + (size_t)r * DIM + db + ksrc, lds);
    }
  };
  auto stageB = [&](int t, int nh) {
    const int buf = t & 1, db = t << 6;
    #pragma unroll
    for (int j = 0; j < 2; ++j) {
      const int piece = j * 2 + wr;
      const int r = piece * 64 + nh * 32 + (wv & 3) * 8 + (lane >> 3);
      const int ksrc = ((lane & 7) * 8) ^ (((r >> 1) & 7) << 3);
      char* lds = (char*)&Bs[buf][0] + piece * 8192 + nh * 4096 + (wv & 3) * 1024;
      gload_lds16(Bb + (size_t)r * DIM + db + ksrc, lds);
    }
  };

  // ---- hoisted swizzled read addresses (per-lane constants) ----
  const int swz = ((l15 >> 1) & 7) << 4;       // byte bits 4-6
  const int kb0 = (l4 * 16) ^ swz;
  const int aB0 = wr * 16384 + l15 * 128 + kb0;
  const int aB1 = aB0 ^ 64;                    // ks=1 flips byte-bit 6
  const int bB0 = wc * 8192 + l15 * 128 + kb0;
  const int bB1 = bB0 ^ 64;

  short8 a[8], b0[4], b1[4];
  auto LDA = [&](int buf, int mh) {            // 8 x ds_read_b128
    const char* base = (const char*)&As[buf][0] + mh * 8192;
    #pragma unroll
    for (int f = 0; f < 4; ++f) {
      a[f * 2 + 0] = *(const short8*)(base + aB0 + f * 2048);
      a[f * 2 + 1] = *(const short8*)(base + aB1 + f * 2048);
    }
  };
  auto LDB0 = [&](int buf) {                   // nh=0 -> b0
    const char* base = (const char*)&Bs[buf][0];
    #pragma unroll
    for (int g = 0; g < 2; ++g) {
      b0[g * 2 + 0] = *(const short8*)(base + bB0 + g * 2048);
      b0[g * 2 + 1] = *(const short8*)(base + bB1 + g * 2048);
    }
  };
  auto LDB1 = [&](int buf) {                   // nh=1 -> b1
    const char* base = (const char*)&Bs[buf][0] + 4096;
    #pragma unroll
    for (int g = 0; g < 2; ++g) {
      b1[g * 2 + 0] = *(const short8*)(base + bB0 + g * 2048);
      b1[g * 2 + 1] = *(const short8*)(base + bB1 + g * 2048);
    }
  };
  auto MFMAQ0 = [&](int mh) {                  // 16 MFMA, nh=0 quadrant
    __builtin_amdgcn_s_setprio(1);
    #pragma unroll
    for (int ks = 0; ks < 2; ++ks)
      #pragma unroll
      for (int f = 0; f < 4; ++f)
        #pragma unroll
        for (int g = 0; g < 2; ++g)
          acc[mh * 4 + f][g] = __builtin_amdgcn_mfma_f32_16x16x32_bf16(
              a[f * 2 + ks], b0[g * 2 + ks], acc[mh * 4 + f][g], 0, 0, 0);
    __builtin_amdgcn_s_setprio(0);
  };
  auto MFMAQ1 = [&](int mh) {                  // 16 MFMA, nh=1 quadrant
    __builtin_amdgcn_s_setprio(1);
    #pragma unroll
    for (int ks = 0; ks < 2; ++ks)
      #pragma unroll
      for (int f = 0; f < 4; ++f)
        #pragma unroll
        for (int g = 0; g < 2; ++g)
          acc[mh * 4 + f][2 + g] = __builtin_amdgcn_mfma_f32_16x16x32_bf16(
              a[f * 2 + ks], b1[g * 2 + ks], acc[mh * 4 + f][2 + g], 0, 0, 0);
    __builtin_amdgcn_s_setprio(0);
  };

  // ---- prologue: stage tiles 0 and 1 fully (16 loads), drain tile 0 ----
  stageA(0, 0); stageA(0, 1); stageB(0, 0); stageB(0, 1);
  stageA(1, 0); stageA(1, 1); stageB(1, 0); stageB(1, 1);
  VMC(8);
  BAR();

  // ---- main loop u=0..13: read tile u (buf), stage tile u+2 (same buf) ----
  // Region ledger: A0 read ph0 / staged ph1; B0 read ph0 / staged ph2;
  //                A1 read ph2 / staged ph3; B1 read ph1 / staged ph3.
  // VMC(8) at ph3 end drains tile u+1 (8 loads), leaves tile u+2 (8) in flight.
  for (int u = 0; u < 14; ++u) {
    const int buf = u & 1;
    LDA(buf, 0); LDB0(buf);
    BAR(); MFMAQ0(0); BAR();
    LDB1(buf); stageA(u + 2, 0);
    BAR(); MFMAQ1(0); BAR();
    LDA(buf, 1); stageB(u + 2, 0);
    BAR(); MFMAQ0(1); BAR();
    stageA(u + 2, 1); stageB(u + 2, 1);
    BAR(); MFMAQ1(1); VMC(8); BAR();
  }
  // ---- u=14 (buf 0): no staging; drain tile 15 at end ----
  LDA(0, 0); LDB0(0);
  BAR(); MFMAQ0(0); BAR();
  LDB1(0);
  BAR(); MFMAQ1(0); BAR();
  LDA(0, 1);
  BAR(); MFMAQ0(1); BAR();
  MFMAQ1(1); VMC(0); BAR();
  // ---- u=15 (buf 1): no staging, no vmcnt ----
  LDA(1, 0); LDB0(1);
  BAR(); MFMAQ0(0); BAR();
  LDB1(1);
  BAR(); MFMAQ1(0); BAR();
  LDA(1, 1);
  BAR(); MFMAQ0(1); BAR();
  MFMAQ1(1);

  // ---- gated epilogue: tanh(AV+Vb)*sigmoid(AU+Ub)*ww, reduce 16 lanes ----
  float partial[8][4];
  #pragma unroll
  for (int f = 0; f < 8; ++f)
    #pragma unroll
    for (int r = 0; r < 4; ++r) partial[f][r] = 0.f;

  #pragma unroll
  for (int p = 0; p < 2; ++p) {
    const int hl = (cb * 8 + wc * 2 + p) * 16 + l15;   // head-local h
    const float vb  = Vb[kh * HID + hl];
    const float ub  = Ub[kh * HID + hl];
    const float wwv = ww[kh * HID + hl];
    #pragma unroll
    for (int f = 0; f < 8; ++f)
      #pragma unroll
      for (int r = 0; r < 4; ++r) {
        const float xv = acc[f][2 * p][r] + vb;
        const float e2 = __expf(2.f * xv);
        const float av = 1.f - 2.f / (e2 + 1.f);       // tanh
        const float xu = acc[f][2 * p + 1][r] + ub;
        const float au = 1.f / (1.f + __expf(-xu));    // sigmoid
        partial[f][r] += av * au * wwv;
      }
  }
  #pragma unroll
  for (int s = 1; s < 16; s <<= 1)
    #pragma unroll
    for (int f = 0; f < 8; ++f)
      #pragma unroll
      for (int r = 0; r < 4; ++r)
        partial[f][r] += __shfl_xor(partial[f][r], s, 64);

  if (l15 == 0) {
    const int j = cb * 4 + wc;   // 0..15 partial slot
    float* dst = part + ((size_t)j * NHEAD + kh) * N_PATCH;
    const int rbase = mt * 256 + wr * 128 + l4 * 4;
    #pragma unroll
    for (int f = 0; f < 8; ++f)
      #pragma unroll
      for (int r = 0; r < 4; ++r)
        dst[rbase + f * 16 + r] = partial[f][r];
  }
}

// ---------------- per-head: sum 16 partials -> scores + softmax stats ----------------
__global__ void scores_stats_kernel(const float* __restrict__ part,
                                    float* __restrict__ scores,
                                    float* __restrict__ stats) {
  const int k = blockIdx.x;
  const int t = threadIdx.x;
  __shared__ float shm[4], shs[4];
  float v[32];
  float mx = -1e30f;
  #pragma unroll
  for (int i = 0; i < 32; ++i) {
    const int n = i * 256 + t;
    float s = 0.f;
    #pragma unroll
    for (int j = 0; j < 16; ++j) s += part[((size_t)j * NHEAD + k) * N_PATCH + n];
    v[i] = s;
    scores[(size_t)k * N_PATCH + n] = s;
    mx = fmaxf(mx, s);
  }
  #pragma unroll
  for (int sft = 32; sft; sft >>= 1) mx = fmaxf(mx, __shfl_xor(mx, sft, 64));
  const int wv = t >> 6;
  if ((t & 63) == 0) shm[wv] = mx;
  __syncthreads();
  mx = fmaxf(fmaxf(shm[0], shm[1]), fmaxf(shm[2], shm[3]));
  float sum = 0.f;
  #pragma unroll
  for (int i = 0; i < 32; ++i) sum += __expf(v[i] - mx);
  #pragma unroll
  for (int sft = 32; sft; sft >>= 1) sum += __shfl_xor(sum, sft, 64);
  if ((t & 63) == 0) shs[wv] = sum;
  __syncthreads();
  if (t == 0) {
    stats[2 * k] = mx;
    stats[2 * k + 1] = shs[0] + shs[1] + shs[2] + shs[3];
  }
}

// ---------------- w[n] = sum_k softmax_k(n) ----------------
__global__ void compute_w_kernel(const float* __restrict__ scores,
                                 const float* __restrict__ stats,
                                 float* __restrict__ w) {
  int n = blockIdx.x * 256 + threadIdx.x;
  float acc = 0.f;
  #pragma unroll
  for (int k = 0; k < NHEAD; ++k) {
    float rl = 1.f / stats[2 * k + 1];
    acc += __expf(scores[(size_t)k * N_PATCH + n] - stats[2 * k]) * rl;
  }
  w[n] = acc;
}

// ---------------- y1[d]=sum w[n]x[n,d], y2[d]=sum x[n,d]  (partials) ----------------
__global__ void weighted_part_kernel(const float* __restrict__ x,
                                     const float* __restrict__ w,
                                     float* __restrict__ wp1,
                                     float* __restrict__ wp2) {
  const int d = blockIdx.x * 256 + threadIdx.x;  // grid.x = 4
  const int nc = blockIdx.y;                     // 32 chunks of 256 rows
  float a1 = 0.f, a2 = 0.f;
  for (int i = 0; i < 256; ++i) {
    int n = nc * 256 + i;
    float xv = x[(size_t)n * DIM + d];
    a1 += w[n] * xv;
    a2 += xv;
  }
  wp1[nc * DIM + d] = a1;
  wp2[nc * DIM + d] = a2;
}

__global__ void reduce_vec_kernel(const float* __restrict__ wp1,
                                  const float* __restrict__ wp2,
                                  float* __restrict__ y1,
                                  float* __restrict__ mvec) {
  int d = blockIdx.x * 256 + threadIdx.x;
  float s1 = 0.f, s2 = 0.f;
  #pragma unroll
  for (int i = 0; i < 32; ++i) {
    s1 += wp1[i * DIM + d];
    s2 += wp2[i * DIM + d];
  }
  y1[d] = s1;
  mvec[d] = s2 * (1.f / (float)N_PATCH);
}

// ---------------- split-K GEMV partial ----------------
__global__ void gemv_part_kernel(const float* __restrict__ in,
                                 const float* __restrict__ W,
                                 float* __restrict__ part, int In, int Out) {
  int j = blockIdx.x * blockDim.x + threadIdx.x;
  int kc = blockIdx.y;
  int chunk = In / gridDim.y;
  if (j >= Out) return;
  const float* Wp = W + (size_t)(kc * chunk) * Out + j;
  float acc = 0.f;
  for (int d = 0; d < chunk; ++d) acc += in[kc * chunk + d] * Wp[(size_t)d * Out];
  part[kc * Out + j] = acc;
}

__global__ void gemv_combine_kernel(const float* __restrict__ part, int nkc,
                                    const float* __restrict__ bias,
                                    const float* __restrict__ extra, float scale,
                                    int do_relu, float* __restrict__ out, int Out) {
  int j = blockIdx.x * blockDim.x + threadIdx.x;
  if (j >= Out) return;
  float v = bias[j];
  for (int kc = 0; kc < nkc; ++kc) v += part[kc * Out + j];
  if (extra) v += extra[j];
  v *= scale;
  if (do_relu) v = fmaxf(v, 0.f);
  out[j] = v;
}

// ---------------- final: logits = c3 @ cW4 + cb4 ; softmax -> out ----------------
__global__ void final_head_kernel(const float* __restrict__ c3,
                                  const float* __restrict__ W,
                                  const float* __restrict__ b,
                                  float* __restrict__ out) {
  __shared__ float logits[9];
  int t = threadIdx.x;
  if (t < 9) {
    float acc = b[t];
    for (int d = 0; d < 256; ++d) acc += c3[d] * W[d * 9 + t];
    logits[t] = acc;
  }
  __syncthreads();
  if (t == 0) {
    float mx = logits[0];
    for (int j = 1; j < 9; ++j) mx = fmaxf(mx, logits[j]);
    float e[9], s = 0.f;
    for (int j = 0; j < 9; ++j) { e[j] = expf(logits[j] - mx); s += e[j]; }
    for (int j = 0; j < 9; ++j) out[j] = e[j] / s;
  }
}

extern "C" void kernel_launch(void* const* d_in, const int* in_sizes, int n_in,
                              void* d_out, int out_size, void* d_ws, size_t ws_size,
                              hipStream_t stream) {
  (void)in_sizes; (void)n_in; (void)out_size; (void)ws_size;
  const float* x   = (const float*)d_in[0];
  const float* Vw  = (const float*)d_in[1];
  const float* Vb  = (const float*)d_in[2];
  const float* Uw  = (const float*)d_in[3];
  const float* Ub  = (const float*)d_in[4];
  const float* ww  = (const float*)d_in[5];
  // d_in[6] = wb: constant per head -> softmax invariant -> unused
  const float* pW1 = (const float*)d_in[7];
  const float* pb1 = (const float*)d_in[8];
  const float* pW2 = (const float*)d_in[9];
  const float* pb2 = (const float*)d_in[10];
  const float* cW1 = (const float*)d_in[11];
  const float* cb1 = (const float*)d_in[12];
  const float* cW2 = (const float*)d_in[13];
  const float* cb2 = (const float*)d_in[14];
  const float* cW3 = (const float*)d_in[15];
  const float* cb3 = (const float*)d_in[16];
  const float* cW4 = (const float*)d_in[17];
  const float* cb4 = (const float*)d_in[18];
  float* out = (float*)d_out;

  char* ws = (char*)d_ws;
  size_t o = 0;
  auto alloc = [&](size_t bytes) -> char* {
    char* p = ws + o;
    o += (bytes + 255) & ~(size_t)255;
    return p;
  };
  unsigned short* xb  = (unsigned short*)alloc((size_t)N_PATCH * DIM * 2);      // 16 MB
  unsigned short* Wpt = (unsigned short*)alloc((size_t)NHEAD * 1024 * DIM * 2); // 32 MB
  float* part   = (float*)alloc((size_t)16 * NHEAD * N_PATCH * 4);              // 8 MB
  float* scores = (float*)alloc((size_t)NHEAD * N_PATCH * 4);
  float* stats  = (float*)alloc(NHEAD * 2 * 4);
  float* wvec   = (float*)alloc(N_PATCH * 4);
  float* wp1    = (float*)alloc(32 * DIM * 4);
  float* wp2    = (float*)alloc(32 * DIM * 4);
  float* y1     = (float*)alloc(DIM * 4);
  float* mvec   = (float*)alloc(DIM * 4);
  float* h1part = (float*)alloc(16 * HID * 4);
  float* h1     = (float*)alloc(HID * 4);
  float* agpart = (float*)alloc(8 * DIM * 4);
  float* aggr   = (float*)alloc(DIM * 4);
  float* c1part = (float*)alloc(16 * 1024 * 4);
  float* c1     = (float*)alloc(1024 * 4);
  float* c2part = (float*)alloc(16 * 512 * 4);
  float* c2     = (float*)alloc(512 * 4);
  float* c3part = (float*)alloc(8 * 256 * 4);
  float* c3     = (float*)alloc(256 * 4);

  convert_x_kernel<<<2048, 256, 0, stream>>>(x, xb);
  pack_w_kernel<<<dim3(8, 16, 16), 256, 0, stream>>>(Vw, Uw, Wpt);
  gemm_scores_kernel<<<2048, 512, 0, stream>>>(xb, Wpt, Vb, Ub, ww, part);
  scores_stats_kernel<<<16, 256, 0, stream>>>(part, scores, stats);
  compute_w_kernel<<<32, 256, 0, stream>>>(scores, stats, wvec);
  weighted_part_kernel<<<dim3(4, 32), 256, 0, stream>>>(x, wvec, wp1, wp2);
  reduce_vec_kernel<<<4, 256, 0, stream>>>(wp1, wp2, y1, mvec);
  gemv_part_kernel<<<dim3(2, 16), 256, 0, stream>>>(mvec, pW1, h1part, DIM, HID);
  gemv_combine_kernel<<<2, 256, 0, stream>>>(h1part, 16, pb1, nullptr, 1.f, 1, h1, HID);
  gemv_part_kernel<<<dim3(4, 8), 256, 0, stream>>>(h1, pW2, agpart, HID, DIM);
  gemv_combine_kernel<<<4, 256, 0, stream>>>(agpart, 8, pb2, y1, 1.f / 17.f, 0, aggr, DIM);
  gemv_part_kernel<<<dim3(4, 16), 256, 0, stream>>>(aggr, cW1, c1part, 1024, 1024);
  gemv_combine_kernel<<<4, 256, 0, stream>>>(c1part, 16, cb1, nullptr, 1.f, 1, c1, 1024);
  gemv_part_kernel<<<dim3(2, 16), 256, 0, stream>>>(c1, cW2, c2part, 1024, 512);
  gemv_combine_kernel<<<2, 256, 0, stream>>>(c2part, 16, cb2, nullptr, 1.f, 1, c2, 512);
  gemv_part_kernel<<<dim3(1, 8), 256, 0, stream>>>(c2, cW3, c3part, 512, 256);
  gemv_combine_kernel<<<1, 256, 0, stream>>>(c3part, 8, cb3, nullptr, 1.f, 1, c3, 256);
  final_head_kernel<<<1, 64, 0, stream>>>(c3, cW4, cb4, out);
}